// Round 5
// baseline (287.189 us; speedup 1.0000x reference)
//
#include <hip/hip_runtime.h>
#include <math.h>

#define BDIM 64
#define HDIM 512
#define WDIM 512
#define KW   31
#define PAD  15
#define INV_KK (1.0f / 961.0f)
#define TH   64                       // output rows per block
#define NPIX ((size_t)BDIM * HDIM * WDIM)

// acc[0]: bce sum; acc[1..64]: inter[b]; acc[65..128]: union[b]
#define NACC 129

__global__ void zero_acc_kernel(double* acc) {
    int i = threadIdx.x;
    if (i < NACC) acc[i] = 0.0;
}

// ---- DPP helpers: VALU cross-lane (single v_add_f32_dpp each) -----------
template<int CTRL, int RMASK>
__device__ __forceinline__ float dpp_add(float p) {
    int t = __builtin_amdgcn_update_dpp(0, __builtin_bit_cast(int, p),
                                        CTRL, RMASK, 0xf, true);
    return p + __builtin_bit_cast(float, t);
}

// inclusive prefix sum over 64 lanes
__device__ __forceinline__ float wave_iscan(float p) {
    p = dpp_add<0x111, 0xf>(p);   // row_shr:1
    p = dpp_add<0x112, 0xf>(p);   // row_shr:2
    p = dpp_add<0x114, 0xf>(p);   // row_shr:4
    p = dpp_add<0x118, 0xf>(p);   // row_shr:8
    p = dpp_add<0x142, 0xa>(p);   // row_bcast:15 -> rows 1,3
    p = dpp_add<0x143, 0xc>(p);   // row_bcast:31 -> rows 2,3
    return p;
}

// inclusive prefix valid through lane 31 (we only use lanes 0..29)
__device__ __forceinline__ float wave_iscan30(float p) {
    p = dpp_add<0x111, 0xf>(p);
    p = dpp_add<0x112, 0xf>(p);
    p = dpp_add<0x114, 0xf>(p);
    p = dpp_add<0x118, 0xf>(p);
    p = dpp_add<0x142, 0xa>(p);
    return p;
}

// lane i <- lane i-1 (lane 0 -> 0)
__device__ __forceinline__ float wave_shr1(float p) {
    int t = __builtin_amdgcn_update_dpp(0, __builtin_bit_cast(int, p),
                                        0x138 /*WAVE_SHR1*/, 0xf, 0xf, true);
    return __builtin_bit_cast(float, t);
}

// Block = 256 threads = 4 waves; each wave owns a 64-col strip and computes
// the horizontal 31-box via DPP prefix scans over a redundant +/-15 halo.
// Vertical 31-box via a 31-deep REGISTER ring: loop is structured as 31-row
// unrolled bodies so every ring index is compile-time (slot = r mod 31, and
// bodies start at r = 0, 31, 62 -> slot sequence 0..30 each time).
// Zero LDS in the main loop, zero barriers -> occupancy is VGPR-limited.
__global__ __launch_bounds__(256, 5)
void fused_kernel(const float* __restrict__ pred,
                  const float* __restrict__ mask,
                  double* __restrict__ acc) {
    __shared__ float red[3][4];

    const int b    = blockIdx.x;
    const int y0   = blockIdx.y * TH;
    const int x    = blockIdx.z * 256 + threadIdx.x;   // output column
    const int lane = threadIdx.x & 63;
    const int wv   = threadIdx.x >> 6;
    const int s    = blockIdx.z * 256 + wv * 64;       // strip start column

    const float* mbase = mask + (size_t)b * HDIM * WDIM;
    const float* pbase = pred + (size_t)b * HDIM * WDIM;

    const int acol = s - 15 + lane;          // halo col, positions 0..63
    const int bcol = s + 49 + lane;          // halo col, positions 64..93
    const bool a_ok = (acol >= 0) && (acol < WDIM);
    const bool b_ok = (lane < 30) && (bcol < WDIM);
    const int hi_lane = (lane + 30) & 63;

    const int tstart = y0 - PAD;             // 94 rows total: r = 0..93

    float bce_acc = 0.f, inter_acc = 0.f, uni_acc = 0.f;

    // horizontal 31-box for mask row t (zero outside [0,H))
    auto hrow = [&](int t) -> float {
        float A = 0.f, B = 0.f;
        if ((unsigned)t < (unsigned)HDIM) {
            const float* rp = mbase + (size_t)t * WDIM;
            if (a_ok) A = rp[acol];
            if (b_ok) B = rp[bcol];
        }
        float pa = wave_iscan(A);            // prefix over positions 0..63
        float pb = wave_iscan30(B);          // prefix over positions 64..93
        const float atot = __builtin_bit_cast(float,
            __builtin_amdgcn_readlane(__builtin_bit_cast(int, pa), 63));
        const float v1 = __shfl(pa, hi_lane);
        const float v2 = __shfl(pb, hi_lane);
        const float Phi = (lane <= 33) ? v1 : (atot + v2);
        const float Plo = wave_shr1(pa);
        return Phi - Plo;                    // hs[x] = P94[l+30] - P94[l-1]
    };

    auto emit = [&](int t, float vsv) {
        const size_t off = (size_t)(t - PAD) * WDIM + x;
        const float M = mbase[off];
        const float P = pbase[off];
        const float box  = vsv * INV_KK;
        const float weit = 1.f + 5.f * fabsf(box - M);
        const float e1   = __expf(-fabsf(P));
        const float bce  = fmaxf(P, 0.f) - P * M + __logf(1.f + e1);
        const float sp   = __builtin_amdgcn_rcpf(1.f + __expf(-P));
        bce_acc   += bce;
        inter_acc += sp * M * weit;
        uni_acc   += (sp + M) * weit;
    };

    float ring[31];                          // register-resident
    float vs = 0.f;

    // ---- warmup: r = 0..29 (fill window, no emit) ----
#pragma unroll
    for (int r = 0; r < 30; ++r) {
        const float h = hrow(tstart + r);
        vs += h;
        ring[r] = h;
    }
    // ---- r = 30: window complete, first emit ----
    {
        const float h = hrow(tstart + 30);
        vs += h;
        ring[30] = h;
        emit(tstart + 30, vs);
    }
    // ---- steady: r = 31..92, two 31-row bodies (keep outer loop rolled) ----
#pragma unroll 1
    for (int rep = 0; rep < 2; ++rep) {
        const int t0 = tstart + 31 + rep * 31;
#pragma unroll
        for (int i = 0; i < 31; ++i) {       // slot i == r mod 31
            const float h = hrow(t0 + i);
            vs += h - ring[i];
            ring[i] = h;
            emit(t0 + i, vs);
        }
    }
    // ---- tail: r = 93 (slot 0) ----
    {
        const float h = hrow(tstart + 93);
        vs += h - ring[0];
        emit(tstart + 93, vs);
    }

    // ---- block reduction (4 waves) ----
#pragma unroll
    for (int off = 32; off > 0; off >>= 1) {
        bce_acc   += __shfl_down(bce_acc, off);
        inter_acc += __shfl_down(inter_acc, off);
        uni_acc   += __shfl_down(uni_acc, off);
    }
    if (lane == 0) {
        red[0][wv] = bce_acc;
        red[1][wv] = inter_acc;
        red[2][wv] = uni_acc;
    }
    __syncthreads();
    if (threadIdx.x == 0) {
        float bs = 0.f, is = 0.f, us = 0.f;
#pragma unroll
        for (int w = 0; w < 4; ++w) { bs += red[0][w]; is += red[1][w]; us += red[2][w]; }
        atomicAdd(&acc[0],      (double)bs);
        atomicAdd(&acc[1 + b],  (double)is);
        atomicAdd(&acc[65 + b], (double)us);
    }
}

__global__ void finalize_kernel(const double* __restrict__ acc, float* __restrict__ out) {
    const int b = threadIdx.x;   // one wave
    double inter = acc[1 + b];
    double uni   = acc[65 + b];
    double wiou  = 1.0 - (inter + 1.0) / (uni - inter + 1.0);
#pragma unroll
    for (int off = 32; off > 0; off >>= 1) wiou += __shfl_down(wiou, off);
    if (b == 0) {
        double wbce = acc[0] / (double)NPIX;
        out[0] = (float)(wbce + wiou / (double)BDIM);
    }
}

extern "C" void kernel_launch(void* const* d_in, const int* in_sizes, int n_in,
                              void* d_out, int out_size, void* d_ws, size_t ws_size,
                              hipStream_t stream) {
    const float* pred = (const float*)d_in[0];
    const float* mask = (const float*)d_in[1];
    float* out = (float*)d_out;
    double* acc = (double*)d_ws;

    zero_acc_kernel<<<1, 256, 0, stream>>>(acc);

    dim3 grid(BDIM, HDIM / TH, WDIM / 256);
    fused_kernel<<<grid, 256, 0, stream>>>(pred, mask, acc);

    finalize_kernel<<<1, 64, 0, stream>>>(acc, out);
}

// Round 6
// 179.615 us; speedup vs baseline: 1.5989x; 1.5989x over previous
//
#include <hip/hip_runtime.h>
#include <math.h>

#define BDIM 64
#define HDIM 512
#define WDIM 512
#define KW   31
#define PAD  15
#define INV_KK (1.0f / 961.0f)
#define TH   128                      // output rows per block
#define BAND 256                      // columns per block
#define NPIX ((size_t)BDIM * HDIM * WDIM)

// acc[0]: bce sum; acc[1..64]: inter[b]; acc[65..128]: union[b]
#define NACC 129

__global__ void zero_acc_kernel(double* acc) {
    int i = threadIdx.x;
    if (i < NACC) acc[i] = 0.0;
}

// ---- DPP helpers: VALU cross-lane (single v_add_f32_dpp each) -----------
template<int CTRL, int RMASK>
__device__ __forceinline__ float dpp_add(float p) {
    int t = __builtin_amdgcn_update_dpp(0, __builtin_bit_cast(int, p),
                                        CTRL, RMASK, 0xf, true);
    return p + __builtin_bit_cast(float, t);
}

// inclusive prefix sum over 64 lanes
__device__ __forceinline__ float wave_iscan(float p) {
    p = dpp_add<0x111, 0xf>(p);   // row_shr:1
    p = dpp_add<0x112, 0xf>(p);   // row_shr:2
    p = dpp_add<0x114, 0xf>(p);   // row_shr:4
    p = dpp_add<0x118, 0xf>(p);   // row_shr:8
    p = dpp_add<0x142, 0xa>(p);   // row_bcast:15 -> rows 1,3
    p = dpp_add<0x143, 0xc>(p);   // row_bcast:31 -> rows 2,3
    return p;
}

// inclusive prefix valid through lane 31 (we only use lanes 0..29)
__device__ __forceinline__ float wave_iscan30(float p) {
    p = dpp_add<0x111, 0xf>(p);
    p = dpp_add<0x112, 0xf>(p);
    p = dpp_add<0x114, 0xf>(p);
    p = dpp_add<0x118, 0xf>(p);
    p = dpp_add<0x142, 0xa>(p);
    return p;
}

// lane i <- lane i-1 (lane 0 -> 0)
__device__ __forceinline__ float wave_shr1(float p) {
    int t = __builtin_amdgcn_update_dpp(0, __builtin_bit_cast(int, p),
                                        0x138 /*WAVE_SHR1*/, 0xf, 0xf, true);
    return __builtin_bit_cast(float, t);
}

// Block = 256 threads = 4 waves over a 256-col band, 128 output rows.
// Horizontal 31-box: per-wave DPP prefix scans over redundant +/-15 halo.
// Vertical 31-box: LDS ring (thread-private slots, no barriers), ring reads
// prefetched 2 rows ahead. Global loads prefetched 4 rows ahead (3-stage
// software pipeline) to cover ~900cyc HBM latency. No barriers in main loop.
__global__ __launch_bounds__(256, 2)
void fused_kernel(const float* __restrict__ pred,
                  const float* __restrict__ mask,
                  double* __restrict__ acc) {
    __shared__ float ring[32][BAND];  // 32 KiB
    __shared__ float red[3][4];

    const int b    = blockIdx.x;
    const int y0   = blockIdx.y * TH;
    const int tid  = threadIdx.x;
    const int lane = tid & 63;
    const int wv   = tid >> 6;
    const int x    = blockIdx.z * BAND + tid;        // output column
    const int s    = blockIdx.z * BAND + wv * 64;    // strip start column

    const float* mbase = mask + (size_t)b * HDIM * WDIM;
    const float* pbase = pred + (size_t)b * HDIM * WDIM;

    const int acol = s - 15 + lane;          // halo col, positions 0..63
    const int bcol = s + 49 + lane;          // halo col, positions 64..93
    const bool a_ok = (acol >= 0) && (acol < WDIM);
    const bool b_ok = (lane < 30) && (bcol < WDIM);
    const int hi_lane = (lane + 30) & 63;

    const int tstart = y0 - PAD;
    const int tend   = y0 + TH - 1 + PAD;    // 158 rows total

    float vs = 0.f;
    float bce_acc = 0.f, inter_acc = 0.f, uni_acc = 0.f;

    auto load_halo = [&](int t, float& A, float& B) {
        A = 0.f; B = 0.f;
        if ((unsigned)t < (unsigned)HDIM) {
            const float* rp = mbase + (size_t)t * WDIM;
            if (a_ok) A = rp[acol];
            if (b_ok) B = rp[bcol];
        }
    };
    auto load_emit = [&](int t, float& M, float& P) {
        M = 0.f; P = 0.f;
        if (t >= y0 + PAD && t <= tend) {
            const size_t off = (size_t)(t - PAD) * WDIM + x;
            M = mbase[off];
            P = pbase[off];
        }
    };

    auto process = [&](int t, float A, float B, float M, float P, float rr) {
        float pa = wave_iscan(A);            // prefix over positions 0..63
        float pb = wave_iscan30(B);          // prefix over positions 64..93
        const float atot = __builtin_bit_cast(float,
            __builtin_amdgcn_readlane(__builtin_bit_cast(int, pa), 63));
        const float v1 = __shfl(pa, hi_lane);
        const float v2 = __shfl(pb, hi_lane);
        const float Phi = (lane <= 33) ? v1 : (atot + v2);
        const float Plo = wave_shr1(pa);
        const float hs  = Phi - Plo;         // hs[x] = P94[l+30] - P94[l-1]

        vs += hs - rr;                       // rr = hs from 31 rows ago (or 0)
        ring[t & 31][tid] = hs;

        if (t >= y0 + PAD) {                 // emit output row yo = t - 15
            const float box  = vs * INV_KK;
            const float weit = 1.f + 5.f * fabsf(box - M);
            const float e1   = __expf(-fabsf(P));
            const float den  = __builtin_amdgcn_rcpf(1.f + e1);
            const float sp   = ((P >= 0.f) ? 1.f : e1) * den;   // sigmoid(P)
            const float bce  = fmaxf(P, 0.f) - P * M + __logf(1.f + e1);
            bce_acc   += bce;
            inter_acc += sp * M * weit;
            uni_acc   += (sp + M) * weit;
        }
    };

    // ---- prime the 3-stage pipeline (rows t..t+3 in flight) ----
    float cA0,cB0,cM0,cP0, cA1,cB1,cM1,cP1;  // rows t, t+1
    float nA0,nB0,nM0,nP0, nA1,nB1,nM1,nP1;  // rows t+2, t+3
    load_halo(tstart,     cA0, cB0); load_emit(tstart,     cM0, cP0);
    load_halo(tstart + 1, cA1, cB1); load_emit(tstart + 1, cM1, cP1);
    load_halo(tstart + 2, nA0, nB0); load_emit(tstart + 2, nM0, nP0);
    load_halo(tstart + 3, nA1, nB1); load_emit(tstart + 3, nM1, nP1);
    float rr0 = 0.f, rr1 = 0.f;              // ring values for rows t, t+1

    for (int t = tstart; t <= tend; t += 2) {   // 79 iterations, 2 rows each
        // issue loads for rows t+4, t+5 (consumed 2 iterations later)
        float fA0=0.f,fB0=0.f,fM0=0.f,fP0=0.f, fA1=0.f,fB1=0.f,fM1=0.f,fP1=0.f;
        if (t + 4 <= tend) { load_halo(t + 4, fA0, fB0); load_emit(t + 4, fM0, fP0); }
        if (t + 5 <= tend) { load_halo(t + 5, fA1, fB1); load_emit(t + 5, fM1, fP1); }

        // prefetch ring values for rows t+2, t+3 (slots not overwritten
        // until rows t+3 / t+4 — after consumption)
        float pr0 = 0.f, pr1 = 0.f;
        if (t + 2 - KW >= tstart) pr0 = ring[(t + 2 - KW) & 31][tid];
        if (t + 3 - KW >= tstart) pr1 = ring[(t + 3 - KW) & 31][tid];

        process(t,     cA0, cB0, cM0, cP0, rr0);
        process(t + 1, cA1, cB1, cM1, cP1, rr1);

        cA0=nA0; cB0=nB0; cM0=nM0; cP0=nP0;
        cA1=nA1; cB1=nB1; cM1=nM1; cP1=nP1;
        nA0=fA0; nB0=fB0; nM0=fM0; nP0=fP0;
        nA1=fA1; nB1=fB1; nM1=fM1; nP1=fP1;
        rr0=pr0; rr1=pr1;
    }

    // ---- block reduction (4 waves) ----
#pragma unroll
    for (int off = 32; off > 0; off >>= 1) {
        bce_acc   += __shfl_down(bce_acc, off);
        inter_acc += __shfl_down(inter_acc, off);
        uni_acc   += __shfl_down(uni_acc, off);
    }
    if (lane == 0) {
        red[0][wv] = bce_acc;
        red[1][wv] = inter_acc;
        red[2][wv] = uni_acc;
    }
    __syncthreads();
    if (threadIdx.x == 0) {
        float bs = 0.f, is = 0.f, us = 0.f;
#pragma unroll
        for (int w = 0; w < 4; ++w) { bs += red[0][w]; is += red[1][w]; us += red[2][w]; }
        atomicAdd(&acc[0],      (double)bs);
        atomicAdd(&acc[1 + b],  (double)is);
        atomicAdd(&acc[65 + b], (double)us);
    }
}

__global__ void finalize_kernel(const double* __restrict__ acc, float* __restrict__ out) {
    const int b = threadIdx.x;   // one wave
    double inter = acc[1 + b];
    double uni   = acc[65 + b];
    double wiou  = 1.0 - (inter + 1.0) / (uni - inter + 1.0);
#pragma unroll
    for (int off = 32; off > 0; off >>= 1) wiou += __shfl_down(wiou, off);
    if (b == 0) {
        double wbce = acc[0] / (double)NPIX;
        out[0] = (float)(wbce + wiou / (double)BDIM);
    }
}

extern "C" void kernel_launch(void* const* d_in, const int* in_sizes, int n_in,
                              void* d_out, int out_size, void* d_ws, size_t ws_size,
                              hipStream_t stream) {
    const float* pred = (const float*)d_in[0];
    const float* mask = (const float*)d_in[1];
    float* out = (float*)d_out;
    double* acc = (double*)d_ws;

    zero_acc_kernel<<<1, 256, 0, stream>>>(acc);

    dim3 grid(BDIM, HDIM / TH, WDIM / BAND);
    fused_kernel<<<grid, 256, 0, stream>>>(pred, mask, acc);

    finalize_kernel<<<1, 64, 0, stream>>>(acc, out);
}